// Round 14
// baseline (436.179 us; speedup 1.0000x reference)
//
#include <hip/hip_runtime.h>
#include <math.h>

#define NN 2048
#define NE 49152
#define WNUM 3328

typedef __attribute__((ext_vector_type(8))) _Float16 half8;
typedef __attribute__((ext_vector_type(4))) float f32x4;

__device__ __forceinline__ float silu_f(float x){ return x / (1.0f + expf(-x)); }
__device__ __forceinline__ float sigm_f(float x){ return 1.0f / (1.0f + expf(-x)); }

// ---------------- fused: edge geometry (192 blocks) | conv_w2 (64 blocks) ----------------
// Independent outputs (egeo/cnt vs w2h), both consumed only by LATER launches — safe
// (R21 lesson: no intra-launch producer-consumer pairs).
// R27: 8x sinf replaced by 1 sincosf + Chebyshev recurrence sin(n*th)=2cos(th)sin((n-1)th)-sin((n-2)th).
#define GB_GEO 192
__global__ void geom_w2_kernel(const float* __restrict__ pos, const int* __restrict__ ei,
                               float* __restrict__ egeo, int* __restrict__ cnt,
                               const float* __restrict__ w2g, _Float16* __restrict__ w2h) {
  if (blockIdx.x >= GB_GEO) {
    // ---- conv_w2: W2 -> f16, MFMA-B-fragment-ordered ----
    int tid = (blockIdx.x - GB_GEO) * 256 + threadIdx.x;
    int j = tid & 7, lane = (tid >> 3) & 63, plane = (tid >> 9) & 1;
    int ct = (tid >> 10) & 3, l = tid >> 12;
    int q = lane >> 4, Lc = lane & 15;
    int k = plane*32 + q*8 + j;
    int n = ct*16 + Lc;
    w2h[tid] = (_Float16)w2g[(size_t)l*4096 + k*64 + n];
    return;
  }
  int e = blockIdx.x * 256 + threadIdx.x;
  int s = ei[e], d = ei[NE + e];
  atomicAdd(&cnt[d], 1);
  float rx = pos[d*3+0] - pos[s*3+0];
  float ry = pos[d*3+1] - pos[s*3+1];
  float rz = pos[d*3+2] - pos[s*3+2];
  float r = sqrtf(rx*rx + ry*ry + rz*rz);
  r = fmaxf(r, 1e-6f);
  float x = rx / r, y = ry / r, z = rz / r;
  const float s3 = 1.7320508075688772f;
  const float c15 = 3.872983346207417f;
  float y2_0 = c15 * x * y;
  float y2_1 = c15 * y * z;
  float y2_2 = 1.118033988749895f * (3.0f*z*z - 1.0f);
  float y2_3 = c15 * x * z;
  float y2_4 = 1.9364916731037085f * (x*x - y*y);
  const float q2 = 0.7071067811865476f;
  const float q6 = 0.4082482904638631f;
  float* g = egeo + (size_t)e * 20;
  g[0] = s3 * x; g[1] = s3 * y; g[2] = s3 * z;
  g[3+0] = -q6*y2_2 + q2*y2_4;
  g[3+1] =  q2*y2_0;
  g[3+2] =  q2*y2_3;
  g[3+3] =  q2*y2_0;
  g[3+4] = -q6*y2_2 - q2*y2_4;
  g[3+5] =  q2*y2_1;
  g[3+6] =  q2*y2_3;
  g[3+7] =  q2*y2_1;
  g[3+8] =  2.0f*q6*y2_2;
  float u = r / 6.0f;
  float fc = 0.0f;
  if (u < 1.0f) {
    float u2=u*u, u3=u2*u, u6=u3*u3, u7=u6*u, u8=u7*u;
    fc = 1.0f - 28.0f*u6 + 48.0f*u7 - 21.0f*u8;
  }
  const float pref = 0.5773502691896258f;
  const float pi6 = 0.5235987755982988f;
  float th = pi6 * r;
  float s1, c1;
  sincosf(th, &s1, &c1);
  float kf = pref * fc / r;
  float c2 = 2.0f * c1;
  float sm2 = 0.0f, sm1 = s1;
  g[12] = kf * s1;
  #pragma unroll
  for (int n = 2; n <= 8; n++) {
    float sn = c2 * sm1 - sm2;
    g[12 + n - 1] = kf * sn;
    sm2 = sm1; sm1 = sn;
  }
}

// ---------------- CSR scan ----------------
__global__ void scan_kernel(const int* __restrict__ cnt, int* __restrict__ offs,
                            int* __restrict__ cursor) {
  __shared__ int part[256];
  int t = threadIdx.x;
  int local[8];
  int s = 0;
  #pragma unroll
  for (int j = 0; j < 8; j++) { local[j] = s; s += cnt[t*8 + j]; }
  part[t] = s;
  __syncthreads();
  for (int off = 1; off < 256; off <<= 1) {
    int v = part[t];
    int add = (t >= off) ? part[t - off] : 0;
    __syncthreads();
    part[t] = v + add;
    __syncthreads();
  }
  int excl = (t == 0) ? 0 : part[t-1];
  #pragma unroll
  for (int j = 0; j < 8; j++) {
    int o = excl + local[j];
    offs[t*8 + j] = o;
    cursor[t*8 + j] = o;
  }
  if (t == 255) offs[2048] = part[255];
}

// ---------------- fused prologue: scatter | conv_w3 | radial_mfma | embed ----
// All sub-kernels depend only on earlier launches; mutually independent.
#define PB_SCAT  192                 // scatter: NE/256
#define PB_W3    208                 // conv_w3: (16*WNUM+255)/256
#define PB_RAD   3072                // radial: 4*(NE/64)
#define PB_EMB   256                 // embed_prep: NN/8
__global__ void prologue_fused_kernel(
    const int* __restrict__ ei, int* __restrict__ cursor, int* __restrict__ epos,
    const float* __restrict__ w3g, _Float16* __restrict__ w3h,
    const _Float16* __restrict__ w2h,
    const float* __restrict__ egeo,
    const float* __restrict__ w1, const float* __restrict__ b1,
    const float* __restrict__ b2, _Float16* __restrict__ f_h,
    const float* __restrict__ x, const float* __restrict__ ew,
    const float* __restrict__ lws0, const float* __restrict__ sws0,
    float* __restrict__ h, _Float16* __restrict__ hx, float* __restrict__ xself) {
  __shared__ float smem[2304];   // radial h1s (64*72 f16) / embed hs
  const int blk = blockIdx.x;
  const int t = threadIdx.x;

  if (blk < PB_SCAT) {
    int e = blk * 256 + t;
    int d = ei[NE + e];
    int p = atomicAdd(&cursor[d], 1);
    epos[e] = p;
  } else if (blk < PB_SCAT + PB_W3) {
    int tid = (blk - PB_SCAT) * 256 + t;
    if (tid >= 16 * WNUM) return;
    int n = tid % WNUM;
    int lq = tid / WNUM;
    int quad = lq & 3, l = lq >> 2;
    const float* src = w3g + (size_t)l * 64 * WNUM + n;
    int idx = n >> 4, L = n & 15;
    _Float16* dst = w3h + ((size_t)(l * 208 + idx) * 2) * 512 + (quad*16 + L) * 8;
    half8 h0, h1;
    #pragma unroll
    for (int j = 0; j < 8; j++) {
      h0[j] = (_Float16)src[(size_t)(quad*8 + j) * WNUM];
      h1[j] = (_Float16)src[(size_t)(32 + quad*8 + j) * WNUM];
    }
    *(half8*)(dst)       = h0;
    *(half8*)(dst + 512) = h1;
  } else if (blk < PB_SCAT + PB_W3 + PB_RAD) {
    // ---- radial MFMA (reads w2h from the geom_w2 launch — safe) ----
    _Float16* h1s = (_Float16*)smem;   // 64*72 f16
    int rb = blk - PB_SCAT - PB_W3;
    const int l = rb / (NE/64);
    const int e0 = (rb % (NE/64)) * 64;
    const float* w1l = w1 + (size_t)l * 512;
    _Float16* fl = f_h + (size_t)l * NE * 64;
    {
      int e = t >> 2, jb = (t & 3) * 16;
      const float* rbp = egeo + (size_t)(e0 + e) * 20 + 12;
      float r0 = rbp[0], r1 = rbp[1], r2 = rbp[2], r3 = rbp[3];
      float r4 = rbp[4], r5 = rbp[5], r6 = rbp[6], r7 = rbp[7];
      #pragma unroll
      for (int jj = 0; jj < 16; ++jj) {
        int j = jb + jj;
        float acc = b1[l*64 + j];
        acc += r0 * w1l[0*64 + j];
        acc += r1 * w1l[1*64 + j];
        acc += r2 * w1l[2*64 + j];
        acc += r3 * w1l[3*64 + j];
        acc += r4 * w1l[4*64 + j];
        acc += r5 * w1l[5*64 + j];
        acc += r6 * w1l[6*64 + j];
        acc += r7 * w1l[7*64 + j];
        h1s[e*72 + j] = (_Float16)silu_f(acc);
      }
    }
    __syncthreads();
    const int wv = t >> 6, lane = t & 63, L = lane & 15, quad = lane >> 4;
    half8 A0 = *(const half8*)&h1s[(wv*16 + L)*72 + quad*8];
    half8 A1 = *(const half8*)&h1s[(wv*16 + L)*72 + 32 + quad*8];
    #pragma unroll
    for (int ct = 0; ct < 4; ++ct) {
      const _Float16* wB = w2h + ((size_t)(l*4 + ct) * 2) * 512 + lane*8;
      half8 B0 = *(const half8*)(wB);
      half8 B1 = *(const half8*)(wB + 512);
      float bb = b2[l*64 + ct*16 + L];
      f32x4 acc = {bb, bb, bb, bb};
      acc = __builtin_amdgcn_mfma_f32_16x16x32_f16(A0, B0, acc, 0, 0, 0);
      acc = __builtin_amdgcn_mfma_f32_16x16x32_f16(A1, B1, acc, 0, 0, 0);
      #pragma unroll
      for (int r = 0; r < 4; ++r) {
        fl[(size_t)(e0 + wv*16 + quad*4 + r)*64 + ct*16 + L] = (_Float16)silu_f(acc[r]);
      }
    }
  } else {
    // ---- embed + layer-0 node linears ----
    float* hs = smem;   // [8][32]
    int rb = blk - PB_SCAT - PB_W3 - PB_RAD;
    int nl = t >> 5, c = t & 31;
    int n = rb * 8 + nl;
    float v = 0.0f;
    #pragma unroll
    for (int j = 0; j < 16; j++) v += x[n*16 + j] * ew[j*32 + c];
    v *= 0.25f;
    hs[nl*32 + c] = v;
    h[(size_t)n*80 + c] = v;
    for (int idx = t; idx < 8*48; idx += 256) {
      int nn = rb * 8 + idx / 48;
      h[(size_t)nn*80 + 32 + idx % 48] = 0.0f;
    }
    __syncthreads();
    for (int idx = t; idx < 2*8*80; idx += 256) {
      int which = idx / 640, r = idx % 640;
      int nl2 = r / 80, cc = r % 80;
      int n2 = rb * 8 + nl2;
      float o = 0.0f;
      if (cc < 32) {
        const float* W = which ? sws0 : lws0;
        #pragma unroll 8
        for (int u = 0; u < 32; u++) o += hs[nl2*32 + u] * W[u*32 + cc];
        o *= 0.17677669529663687f;
      }
      if (which) xself[(size_t)n2*80 + cc] = o;
      else       hx[(size_t)n2*80 + cc] = (_Float16)o;
    }
  }
}

// ---------------- fused MFMA weight-GEMM (f16) + tensor product -> msg (CSR order) ----
// R16-EXACT K-loop — FROZEN, incl. 4-deep prefetch AND f32 LDS operand formats.
// Structural finding (R23/R25/R26/R28): kernel runs at 116 VGPR against a hard
// 128-VGPR allocator budget under (256,2) — ~12 VGPR headroom. Every lever that
// adds live state trips the cliff: 3rd VMEM stream (R23, -50%), +4 prefetch slots
// (R25 spill; R26 at (256,1): 256 VGPR + 372MB scratch), f16 LDS conversion temps
// (R28: 128 VGPR + 25.6MB scratch, occupancy unchanged). Compiler-enforced local
// minimum at ~13% MfmaUtil.
// R24 (kept, verified): bias in LDS, vectorized conflict-free hx gather
// (conflicts 3.86M->442K): e = lane, stride-1 LDS writes, two half8 loads/thread.
__launch_bounds__(256, 2)
__global__ void edge_msg_kernel(const int* __restrict__ ei, const float* __restrict__ egeo,
                                const _Float16* __restrict__ f_h,
                                const _Float16* __restrict__ hx,
                                const _Float16* __restrict__ w3h,
                                const float* __restrict__ b3g,
                                const int* __restrict__ epos,
                                _Float16* __restrict__ msg, int l) {
  __shared__ float smem[15616];            // 62.5 KB
  __shared__ int eposS[64];
  float* sT    = smem;                     // [32][64]
  float* p2T   = smem + 2048;              // [16][64]
  float* q3T   = smem + 3072;              // [48][64]  s_u * y1_i
  float* vT    = smem + 6144;              // [48][64]
  float* q5T   = smem + 9216;              // [48][64]
  float* biasL = smem + 12288;             // [3328]
  float* poolA = smem;                     // post-loop overlay (sT+p2T dead)
  float* poolB = smem + 3072;              // overlay (q3T dead)
  float* poolC = smem + 6144;              // overlay (vT dead)

  const int t = threadIdx.x;
  const int e0 = blockIdx.x * 64;
  const float* b3l = b3g + (size_t)l * WNUM;

  // ---- prologue ----
  for (int i = t; i < WNUM; i += 256) biasL[i] = b3l[i];
  if (t < 64) eposS[t] = epos[e0 + t];
  // vectorized hx gather: e = lane (stride-1 LDS writes, conflict-free; cb wave-uniform)
  for (int idx = t; idx < 64*5; idx += 256) {
    int e = idx & 63, cb = idx >> 6;       // cb in 0..4, 16 channels each
    int src = ei[e0 + e];
    const half8* hp = (const half8*)(hx + (size_t)src*80 + cb*16);
    half8 v0 = hp[0], v1 = hp[1];
    #pragma unroll
    for (int k = 0; k < 8; ++k) {
      int c = cb*16 + k;
      float f = (float)v0[k];
      if (c < 32) sT[c*64 + e] = f; else vT[(c-32)*64 + e] = f;
    }
    #pragma unroll
    for (int k = 0; k < 8; ++k) {
      int c = cb*16 + 8 + k;
      float f = (float)v1[k];
      if (c < 32) sT[c*64 + e] = f; else vT[(c-32)*64 + e] = f;
    }
  }
  __syncthreads();
  for (int idx = t; idx < 64*16; idx += 256) {
    int u = idx >> 6, e = idx & 63;
    const float* g = &egeo[(size_t)(e0+e)*20];
    float a = vT[(u*3)*64+e]*g[0] + vT[(u*3+1)*64+e]*g[1] + vT[(u*3+2)*64+e]*g[2];
    p2T[u*64 + e] = a * 0.5773502691896258f;
  }
  for (int idx = t; idx < 64*48; idx += 256) {
    int o = idx >> 6, e = idx & 63;
    int u = o / 3, jj = o % 3;
    const float* g = &egeo[(size_t)(e0+e)*20];
    q3T[o*64 + e] = sT[u*64 + e] * g[jj];
    float a = vT[(u*3)*64+e]*g[3+jj] + vT[(u*3+1)*64+e]*g[6+jj] + vT[(u*3+2)*64+e]*g[9+jj];
    q5T[o*64 + e] = a * 0.7745966692414834f;
  }

  const int wv = t >> 6, lane = t & 63, L = lane & 15, quad = lane >> 4;
  const int qb = quad * 4;

  // A fragments for all 4 edge-groups (32 VGPR)
  half8 Ah[4][2];
  #pragma unroll
  for (int g = 0; g < 4; ++g) {
    const half8* fA = (const half8*)(f_h + (size_t)(e0 + g*16 + L)*64);
    Ah[g][0] = fA[quad];
    Ah[g][1] = fA[4 + quad];
  }
  __syncthreads();   // LDS (factors + bias + epos) ready

  const _Float16* wb = w3h + (size_t)l * 208 * 1024 + lane * 8;
  half8 pb0[4], pb1[4];
  float bs[4];

#define PRIME(START)                                                          \
  { _Pragma("unroll")                                                         \
    for (int _s = 0; _s < 4; ++_s) {                                          \
      const _Float16* _wn = wb + (size_t)((START) + _s) * 1024;               \
      pb0[_s] = *(const half8*)_wn;                                           \
      pb1[_s] = *(const half8*)(_wn + 512);                                   \
      bs[_s] = biasL[((START) + _s)*16 + L];                                  \
    } }

  // declares a0..a3 (one per edge-group); CO compile-time
#define GCORE(IDX, CO, OKCOND)                                                \
  f32x4 a0, a1, a2, a3;                                                       \
  { half8 _B0 = pb0[(CO)&3], _B1 = pb1[(CO)&3];                               \
    float _bb = bs[(CO)&3];                                                   \
    if (OKCOND) {                                                             \
      const _Float16* _wn = wb + (size_t)((IDX) + 4) * 1024;                  \
      pb0[(CO)&3] = *(const half8*)_wn;                                       \
      pb1[(CO)&3] = *(const half8*)(_wn + 512);                               \
      bs[(CO)&3] = biasL[((IDX) + 4)*16 + L];                                 \
    }                                                                         \
    a0 = (f32x4){_bb,_bb,_bb,_bb}; a1 = a0; a2 = a0; a3 = a0;                 \
    a0 = __builtin_amdgcn_mfma_f32_16x16x32_f16(Ah[0][0], _B0, a0, 0,0,0);    \
    a0 = __builtin_amdgcn_mfma_f32_16x16x32_f16(Ah[0][1], _B1, a0, 0,0,0);    \
    a1 = __builtin_amdgcn_mfma_f32_16x16x32_f16(Ah[1][0], _B0, a1, 0,0,0);    \
    a1 = __builtin_amdgcn_mfma_f32_16x16x32_f16(Ah[1][1], _B1, a1, 0,0,0);    \
    a2 = __builtin_amdgcn_mfma_f32_16x16x32_f16(Ah[2][0], _B0, a2, 0,0,0);    \
    a2 = __builtin_amdgcn_mfma_f32_16x16x32_f16(Ah[2][1], _B1, a2, 0,0,0);    \
    a3 = __builtin_amdgcn_mfma_f32_16x16x32_f16(Ah[3][0], _B0, a3, 0,0,0);    \
    a3 = __builtin_amdgcn_mfma_f32_16x16x32_f16(Ah[3][1], _B1, a3, 0,0,0);    \
  }

  const float S48 = 0.14433756729740645f;  // 1/sqrt(48)
  const float S64 = 0.125f;                // 1/sqrt(64)

  if (wv <= 1) {
    f32x4 ms[4][3];
    #pragma unroll
    for (int g = 0; g < 4; ++g)
      #pragma unroll
      for (int j = 0; j < 3; ++j) ms[g][j] = (f32x4){0,0,0,0};
    const int ustart = wv * 16, istart = wv * 48, iend = istart + 48;
    PRIME(istart);
    for (int u4 = 0; u4 < 16; u4 += 4) {
      #pragma unroll
      for (int uu = 0; uu < 4; ++uu) {
        const int u = u4 + uu;
        f32x4 f0 = *(const f32x4*)&sT[(ustart+u)*64 + qb];
        f32x4 f1 = *(const f32x4*)&sT[(ustart+u)*64 + 16 + qb];
        f32x4 f2 = *(const f32x4*)&sT[(ustart+u)*64 + 32 + qb];
        f32x4 f3 = *(const f32x4*)&sT[(ustart+u)*64 + 48 + qb];
        #pragma unroll
        for (int j = 0; j < 3; ++j) {
          const int CO = uu*3 + j;
          const int idx = istart + u4*3 + CO;
          GCORE(idx, CO, idx + 4 < iend);
          ms[0][j] += f0*a0; ms[1][j] += f1*a1; ms[2][j] += f2*a2; ms[3][j] += f3*a3;
        }
      }
    }
    float* pool = (wv == 0) ? poolA : poolB;
    __syncthreads();
    #pragma unroll
    for (int g = 0; g < 4; ++g)
      #pragma unroll
      for (int j = 0; j < 3; ++j)
        #pragma unroll
        for (int r = 0; r < 4; ++r)
          pool[(g*16 + qb + r)*48 + j*16 + L] = ms[g][j][r];
    __syncthreads();
  } else if (wv == 2) {
    f32x4 ms[4][3], mv[4][3];
    #pragma unroll
    for (int g = 0; g < 4; ++g)
      #pragma unroll
      for (int j = 0; j < 3; ++j) { ms[g][j] = (f32x4){0,0,0,0}; mv[g][j] = (f32x4){0,0,0,0}; }
    PRIME(96);
    for (int u4 = 0; u4 < 16; u4 += 4) {
      #pragma unroll
      for (int uu = 0; uu < 4; ++uu) {
        const int u = u4 + uu;
        f32x4 f0 = *(const f32x4*)&p2T[u*64 + qb];
        f32x4 f1 = *(const f32x4*)&p2T[u*64 + 16 + qb];
        f32x4 f2 = *(const f32x4*)&p2T[u*64 + 32 + qb];
        f32x4 f3 = *(const f32x4*)&p2T[u*64 + 48 + qb];
        #pragma unroll
        for (int j = 0; j < 3; ++j) {
          const int CO = uu*3 + j;
          const int idx = 96 + u4*3 + CO;
          GCORE(idx, CO, idx + 4 < 144);
          ms[0][j] += f0*a0; ms[1][j] += f1*a1; ms[2][j] += f2*a2; ms[3][j] += f3*a3;
        }
      }
    }
    PRIME(176);
    for (int u4 = 0; u4 < 16; u4 += 4) {
      #pragma unroll
      for (int uu = 0; uu < 4; ++uu) {
        const int u = u4 + uu;
        const int idx = 176 + u;
        GCORE(idx, uu, idx + 4 < 192);
        #pragma unroll
        for (int i = 0; i < 3; ++i) {
          mv[0][i] += *(const f32x4*)&vT[(u*3+i)*64 + qb]      * a0;
          mv[1][i] += *(const f32x4*)&vT[(u*3+i)*64 + 16 + qb] * a1;
          mv[2][i] += *(const f32x4*)&vT[(u*3+i)*64 + 32 + qb] * a2;
          mv[3][i] += *(const f32x4*)&vT[(u*3+i)*64 + 48 + qb] * a3;
        }
      }
    }
    __syncthreads();
    #pragma unroll
    for (int g = 0; g < 4; ++g)
      #pragma unroll
      for (int i = 0; i < 3; ++i)
        #pragma unroll
        for (int r = 0; r < 4; ++r)
          poolC[(g*16 + qb + r)*48 + i*16 + L] = mv[g][i][r];
    __syncthreads();
    #pragma unroll
    for (int g = 0; g < 4; ++g) {
      #pragma unroll
      for (int r = 0; r < 4; ++r) {
        const int eb = g*16 + qb + r;
        _Float16* mp = msg + (size_t)eposS[eb]*96;
        #pragma unroll
        for (int j = 0; j < 3; ++j)
          mp[j*16 + L] = (_Float16)((ms[g][j][r] + poolA[eb*48 + j*16 + L] + poolB[eb*48 + j*16 + L]) * S48);
      }
    }
  } else {
    f32x4 mv[4][3];
    #pragma unroll
    for (int g = 0; g < 4; ++g)
      #pragma unroll
      for (int i = 0; i < 3; ++i) mv[g][i] = (f32x4){0,0,0,0};
    PRIME(144);
    for (int u4 = 0; u4 < 32; u4 += 4) {
      #pragma unroll
      for (int uu = 0; uu < 4; ++uu) {
        const int u = u4 + uu;
        const int idx = 144 + u;
        GCORE(idx, uu, idx + 4 < 176);
        #pragma unroll
        for (int i = 0; i < 3; ++i) {
          mv[0][i] += *(const f32x4*)&q3T[(u*3+i)*64 + qb]      * a0;
          mv[1][i] += *(const f32x4*)&q3T[(u*3+i)*64 + 16 + qb] * a1;
          mv[2][i] += *(const f32x4*)&q3T[(u*3+i)*64 + 32 + qb] * a2;
          mv[3][i] += *(const f32x4*)&q3T[(u*3+i)*64 + 48 + qb] * a3;
        }
      }
    }
    PRIME(192);
    for (int u4 = 0; u4 < 16; u4 += 4) {
      #pragma unroll
      for (int uu = 0; uu < 4; ++uu) {
        const int u = u4 + uu;
        const int idx = 192 + u;
        GCORE(idx, uu, idx + 4 < 208);
        #pragma unroll
        for (int i = 0; i < 3; ++i) {
          mv[0][i] += *(const f32x4*)&q5T[(u*3+i)*64 + qb]      * a0;
          mv[1][i] += *(const f32x4*)&q5T[(u*3+i)*64 + 16 + qb] * a1;
          mv[2][i] += *(const f32x4*)&q5T[(u*3+i)*64 + 32 + qb] * a2;
          mv[3][i] += *(const f32x4*)&q5T[(u*3+i)*64 + 48 + qb] * a3;
        }
      }
    }
    __syncthreads();
    __syncthreads();
    #pragma unroll
    for (int g = 0; g < 4; ++g) {
      #pragma unroll
      for (int r = 0; r < 4; ++r) {
        const int eb = g*16 + qb + r;
        _Float16* mp = msg + (size_t)eposS[eb]*96;
        #pragma unroll
        for (int i = 0; i < 3; ++i)
          mp[48 + 3*L + i] = (_Float16)((mv[g][i][r] + poolC[eb*48 + i*16 + L]) * S64);
      }
    }
  }
#undef GCORE
#undef PRIME
}

// ---------------- fused: CSR-streaming gather (f16 msg) + node update + next linears ----
__global__ void agg_fused_kernel(const _Float16* __restrict__ msg, const int* __restrict__ offs,
                                 const float* __restrict__ xself_in, float* __restrict__ h,
                                 const float* __restrict__ lwsN, const float* __restrict__ lwvN,
                                 const float* __restrict__ swsN, const float* __restrict__ swvN,
                                 _Float16* __restrict__ hx_out, float* __restrict__ xself_out,
                                 const float* __restrict__ pw, float* __restrict__ out,
                                 int last) {
  __shared__ float sagg[4][96];
  __shared__ float hnew[4][80];
  int t = threadIdx.x;
  int nb = blockIdx.x * 4;
  for (int idx = t; idx < 4*96; idx += 256) {
    int nl = idx / 96, c = idx % 96;
    int n = nb + nl;
    int b = offs[n], e = offs[n+1];
    float acc = 0.0f, acc2 = 0.0f;
    int j = b;
    for (; j + 1 < e; j += 2) {
      acc  += (float)msg[(size_t)j*96 + c];
      acc2 += (float)msg[(size_t)(j+1)*96 + c];
    }
    if (j < e) acc += (float)msg[(size_t)j*96 + c];
    sagg[nl][c] = (acc + acc2) * 0.20412414523193154f;   // 1/sqrt(24)
  }
  __syncthreads();
  for (int idx = t; idx < 4*80; idx += 256) {
    int nl = idx / 80, c = idx % 80;
    int n = nb + nl;
    float a;
    if (c < 32) {
      a = silu_f(sagg[nl][c]);
    } else {
      int oc = c - 32, wch = oc / 3;
      a = sagg[nl][48 + oc] * sigm_f(sagg[nl][32 + wch]);
    }
    float hn = h[(size_t)n*80 + c] + xself_in[(size_t)n*80 + c] + a;
    hnew[nl][c] = hn;
    h[(size_t)n*80 + c] = hn;
  }
  __syncthreads();
  if (!last) {
    for (int idx = t; idx < 2*4*80; idx += 256) {
      int which = idx / 320, r = idx % 320;
      int nl = r / 80, c = r % 80;
      int n = nb + nl;
      const float* Ws = which ? swsN : lwsN;
      const float* Wv = which ? swvN : lwvN;
      float v = 0.0f;
      if (c < 32) {
        #pragma unroll 8
        for (int u = 0; u < 32; u++) v += hnew[nl][u] * Ws[u*32 + c];
        v *= 0.17677669529663687f;
      } else {
        int oc = c - 32, wch = oc / 3, i = oc % 3;
        #pragma unroll
        for (int u = 0; u < 16; u++) v += hnew[nl][32 + u*3 + i] * Wv[u*16 + wch];
        v *= 0.25f;
      }
      if (which) xself_out[(size_t)n*80 + c] = v;
      else       hx_out[(size_t)n*80 + c] = (_Float16)v;
    }
  } else {
    for (int idx = t; idx < 4*32; idx += 256) {
      int nl = idx / 32, c = idx % 32;
      int n = nb + nl;
      float acc = 0.0f;
      #pragma unroll 8
      for (int u = 0; u < 32; u++) acc += hnew[nl][u] * pw[u*32 + c];
      out[(size_t)n*32 + c] = acc * 0.17677669529663687f;
    }
  }
}

extern "C" void kernel_launch(void* const* d_in, const int* in_sizes, int n_in,
                              void* d_out, int out_size, void* d_ws, size_t ws_size,
                              hipStream_t stream) {
  const float* x       = (const float*)d_in[0];
  const float* pos     = (const float*)d_in[1];
  const int*   ei      = (const int*)  d_in[2];
  const float* embed_w = (const float*)d_in[3];
  const float* proj_w  = (const float*)d_in[4];
  const float* lin_ws  = (const float*)d_in[5];
  const float* lin_wv  = (const float*)d_in[6];
  const float* sc_ws   = (const float*)d_in[7];
  const float* sc_wv   = (const float*)d_in[8];
  const float* mlp_w1  = (const float*)d_in[9];
  const float* mlp_b1  = (const float*)d_in[10];
  const float* mlp_w2  = (const float*)d_in[11];
  const float* mlp_b2  = (const float*)d_in[12];
  const float* mlp_w3  = (const float*)d_in[13];
  const float* mlp_b3  = (const float*)d_in[14];
  float* out = (float*)d_out;

  float* ws    = (float*)d_ws;
  float* egeo  = ws;                          // NE*20
  float* h     = egeo  + (size_t)NE*20;       // NN*80
  float* xself = h     + (size_t)NN*80;       // NN*80
  _Float16* hx  = (_Float16*)(xself + (size_t)NN*80); // NN*80 f16
  _Float16* msg = hx + (size_t)NN*80;                 // NE*96 f16 (CSR-ordered rows)
  _Float16* f_h = msg + (size_t)NE*96;                // 4*NE*64 f16 (all layers)
  _Float16* w3h = f_h + (size_t)4*NE*64;              // 4*208*1024 f16
  _Float16* w2h = w3h + (size_t)4*208*1024;           // 16384 f16 (32 KB)
  int* cnt    = (int*)(w2h + 16384);          // NN
  int* offs   = cnt + NN;                     // NN+1
  int* cursor = offs + NN + 1;                // NN
  int* epos   = cursor + NN;                  // NE

  hipMemsetAsync(cnt, 0, NN*sizeof(int), stream);
  geom_w2_kernel<<<GB_GEO + 64, 256, 0, stream>>>(pos, ei, egeo, cnt, mlp_w2, w2h);
  scan_kernel<<<1, 256, 0, stream>>>(cnt, offs, cursor);
  prologue_fused_kernel<<<PB_SCAT + PB_W3 + PB_RAD + PB_EMB, 256, 0, stream>>>(
      ei, cursor, epos, mlp_w3, w3h, w2h, egeo,
      mlp_w1, mlp_b1, mlp_b2, f_h, x, embed_w, lin_ws, sc_ws, h, hx, xself);

  for (int l = 0; l < 4; l++) {
    edge_msg_kernel<<<NE/64, 256, 0, stream>>>(ei, egeo, f_h + (size_t)l*NE*64, hx,
                                               w3h, mlp_b3, epos, msg, l);
    int last = (l == 3);
    agg_fused_kernel<<<NN/4, 256, 0, stream>>>(
        msg, offs, xself, h,
        lin_ws + (size_t)(l+1 < 4 ? l+1 : 0) * 1024,
        lin_wv + (size_t)(l+1 < 4 ? l+1 : 0) * 256,
        sc_ws  + (size_t)(l+1 < 4 ? l+1 : 0) * 1024,
        sc_wv  + (size_t)(l+1 < 4 ? l+1 : 0) * 256,
        hx, xself, proj_w, out, last);
  }
}

// Round 17
// 399.798 us; speedup vs baseline: 1.0910x; 1.0910x over previous
//
#include <hip/hip_runtime.h>
#include <math.h>

#define NN 2048
#define NE 49152
#define WNUM 3328

typedef __attribute__((ext_vector_type(8))) _Float16 half8;
typedef __attribute__((ext_vector_type(4))) float f32x4;

__device__ __forceinline__ float silu_f(float x){ return x / (1.0f + expf(-x)); }
__device__ __forceinline__ float sigm_f(float x){ return 1.0f / (1.0f + expf(-x)); }

// ---------------- fused: edge geometry (192 blocks) | conv_w2 (64 blocks) ----------------
// Independent outputs (egeo/cnt vs w2h), both consumed only by LATER launches — safe
// (R21 lesson: no intra-launch producer-consumer pairs).
// R27: 8x sinf replaced by 1 sincosf + Chebyshev recurrence sin(n*th)=2cos(th)sin((n-1)th)-sin((n-2)th).
#define GB_GEO 192
__global__ void geom_w2_kernel(const float* __restrict__ pos, const int* __restrict__ ei,
                               float* __restrict__ egeo, int* __restrict__ cnt,
                               const float* __restrict__ w2g, _Float16* __restrict__ w2h) {
  if (blockIdx.x >= GB_GEO) {
    // ---- conv_w2: W2 -> f16, MFMA-B-fragment-ordered ----
    int tid = (blockIdx.x - GB_GEO) * 256 + threadIdx.x;
    int j = tid & 7, lane = (tid >> 3) & 63, plane = (tid >> 9) & 1;
    int ct = (tid >> 10) & 3, l = tid >> 12;
    int q = lane >> 4, Lc = lane & 15;
    int k = plane*32 + q*8 + j;
    int n = ct*16 + Lc;
    w2h[tid] = (_Float16)w2g[(size_t)l*4096 + k*64 + n];
    return;
  }
  int e = blockIdx.x * 256 + threadIdx.x;
  int s = ei[e], d = ei[NE + e];
  atomicAdd(&cnt[d], 1);
  float rx = pos[d*3+0] - pos[s*3+0];
  float ry = pos[d*3+1] - pos[s*3+1];
  float rz = pos[d*3+2] - pos[s*3+2];
  float r = sqrtf(rx*rx + ry*ry + rz*rz);
  r = fmaxf(r, 1e-6f);
  float x = rx / r, y = ry / r, z = rz / r;
  const float s3 = 1.7320508075688772f;
  const float c15 = 3.872983346207417f;
  float y2_0 = c15 * x * y;
  float y2_1 = c15 * y * z;
  float y2_2 = 1.118033988749895f * (3.0f*z*z - 1.0f);
  float y2_3 = c15 * x * z;
  float y2_4 = 1.9364916731037085f * (x*x - y*y);
  const float q2 = 0.7071067811865476f;
  const float q6 = 0.4082482904638631f;
  float* g = egeo + (size_t)e * 20;
  g[0] = s3 * x; g[1] = s3 * y; g[2] = s3 * z;
  g[3+0] = -q6*y2_2 + q2*y2_4;
  g[3+1] =  q2*y2_0;
  g[3+2] =  q2*y2_3;
  g[3+3] =  q2*y2_0;
  g[3+4] = -q6*y2_2 - q2*y2_4;
  g[3+5] =  q2*y2_1;
  g[3+6] =  q2*y2_3;
  g[3+7] =  q2*y2_1;
  g[3+8] =  2.0f*q6*y2_2;
  float u = r / 6.0f;
  float fc = 0.0f;
  if (u < 1.0f) {
    float u2=u*u, u3=u2*u, u6=u3*u3, u7=u6*u, u8=u7*u;
    fc = 1.0f - 28.0f*u6 + 48.0f*u7 - 21.0f*u8;
  }
  const float pref = 0.5773502691896258f;
  const float pi6 = 0.5235987755982988f;
  float th = pi6 * r;
  float s1, c1;
  sincosf(th, &s1, &c1);
  float kf = pref * fc / r;
  float c2 = 2.0f * c1;
  float sm2 = 0.0f, sm1 = s1;
  g[12] = kf * s1;
  #pragma unroll
  for (int n = 2; n <= 8; n++) {
    float sn = c2 * sm1 - sm2;
    g[12 + n - 1] = kf * sn;
    sm2 = sm1; sm1 = sn;
  }
}

// ---------------- CSR scan ----------------
__global__ void scan_kernel(const int* __restrict__ cnt, int* __restrict__ offs,
                            int* __restrict__ cursor) {
  __shared__ int part[256];
  int t = threadIdx.x;
  int local[8];
  int s = 0;
  #pragma unroll
  for (int j = 0; j < 8; j++) { local[j] = s; s += cnt[t*8 + j]; }
  part[t] = s;
  __syncthreads();
  for (int off = 1; off < 256; off <<= 1) {
    int v = part[t];
    int add = (t >= off) ? part[t - off] : 0;
    __syncthreads();
    part[t] = v + add;
    __syncthreads();
  }
  int excl = (t == 0) ? 0 : part[t-1];
  #pragma unroll
  for (int j = 0; j < 8; j++) {
    int o = excl + local[j];
    offs[t*8 + j] = o;
    cursor[t*8 + j] = o;
  }
  if (t == 255) offs[2048] = part[255];
}

// ---------------- fused prologue: scatter | conv_w3 | radial_mfma | embed ----
// All sub-kernels depend only on earlier launches; mutually independent.
#define PB_SCAT  192                 // scatter: NE/256
#define PB_W3    208                 // conv_w3: (16*WNUM+255)/256
#define PB_RAD   3072                // radial: 4*(NE/64)
#define PB_EMB   256                 // embed_prep: NN/8
__global__ void prologue_fused_kernel(
    const int* __restrict__ ei, int* __restrict__ cursor, int* __restrict__ epos,
    const float* __restrict__ w3g, _Float16* __restrict__ w3h,
    const _Float16* __restrict__ w2h,
    const float* __restrict__ egeo,
    const float* __restrict__ w1, const float* __restrict__ b1,
    const float* __restrict__ b2, _Float16* __restrict__ f_h,
    const float* __restrict__ x, const float* __restrict__ ew,
    const float* __restrict__ lws0, const float* __restrict__ sws0,
    float* __restrict__ h, _Float16* __restrict__ hx, float* __restrict__ xself) {
  __shared__ float smem[2304];   // radial h1s (64*72 f16) / embed hs
  const int blk = blockIdx.x;
  const int t = threadIdx.x;

  if (blk < PB_SCAT) {
    int e = blk * 256 + t;
    int d = ei[NE + e];
    int p = atomicAdd(&cursor[d], 1);
    epos[e] = p;
  } else if (blk < PB_SCAT + PB_W3) {
    int tid = (blk - PB_SCAT) * 256 + t;
    if (tid >= 16 * WNUM) return;
    int n = tid % WNUM;
    int lq = tid / WNUM;
    int quad = lq & 3, l = lq >> 2;
    const float* src = w3g + (size_t)l * 64 * WNUM + n;
    int idx = n >> 4, L = n & 15;
    _Float16* dst = w3h + ((size_t)(l * 208 + idx) * 2) * 512 + (quad*16 + L) * 8;
    half8 h0, h1;
    #pragma unroll
    for (int j = 0; j < 8; j++) {
      h0[j] = (_Float16)src[(size_t)(quad*8 + j) * WNUM];
      h1[j] = (_Float16)src[(size_t)(32 + quad*8 + j) * WNUM];
    }
    *(half8*)(dst)       = h0;
    *(half8*)(dst + 512) = h1;
  } else if (blk < PB_SCAT + PB_W3 + PB_RAD) {
    // ---- radial MFMA (reads w2h from the geom_w2 launch — safe) ----
    _Float16* h1s = (_Float16*)smem;   // 64*72 f16
    int rb = blk - PB_SCAT - PB_W3;
    const int l = rb / (NE/64);
    const int e0 = (rb % (NE/64)) * 64;
    const float* w1l = w1 + (size_t)l * 512;
    _Float16* fl = f_h + (size_t)l * NE * 64;
    {
      int e = t >> 2, jb = (t & 3) * 16;
      const float* rbp = egeo + (size_t)(e0 + e) * 20 + 12;
      float r0 = rbp[0], r1 = rbp[1], r2 = rbp[2], r3 = rbp[3];
      float r4 = rbp[4], r5 = rbp[5], r6 = rbp[6], r7 = rbp[7];
      #pragma unroll
      for (int jj = 0; jj < 16; ++jj) {
        int j = jb + jj;
        float acc = b1[l*64 + j];
        acc += r0 * w1l[0*64 + j];
        acc += r1 * w1l[1*64 + j];
        acc += r2 * w1l[2*64 + j];
        acc += r3 * w1l[3*64 + j];
        acc += r4 * w1l[4*64 + j];
        acc += r5 * w1l[5*64 + j];
        acc += r6 * w1l[6*64 + j];
        acc += r7 * w1l[7*64 + j];
        h1s[e*72 + j] = (_Float16)silu_f(acc);
      }
    }
    __syncthreads();
    const int wv = t >> 6, lane = t & 63, L = lane & 15, quad = lane >> 4;
    half8 A0 = *(const half8*)&h1s[(wv*16 + L)*72 + quad*8];
    half8 A1 = *(const half8*)&h1s[(wv*16 + L)*72 + 32 + quad*8];
    #pragma unroll
    for (int ct = 0; ct < 4; ++ct) {
      const _Float16* wB = w2h + ((size_t)(l*4 + ct) * 2) * 512 + lane*8;
      half8 B0 = *(const half8*)(wB);
      half8 B1 = *(const half8*)(wB + 512);
      float bb = b2[l*64 + ct*16 + L];
      f32x4 acc = {bb, bb, bb, bb};
      acc = __builtin_amdgcn_mfma_f32_16x16x32_f16(A0, B0, acc, 0, 0, 0);
      acc = __builtin_amdgcn_mfma_f32_16x16x32_f16(A1, B1, acc, 0, 0, 0);
      #pragma unroll
      for (int r = 0; r < 4; ++r) {
        fl[(size_t)(e0 + wv*16 + quad*4 + r)*64 + ct*16 + L] = (_Float16)silu_f(acc[r]);
      }
    }
  } else {
    // ---- embed + layer-0 node linears ----
    float* hs = smem;   // [8][32]
    int rb = blk - PB_SCAT - PB_W3 - PB_RAD;
    int nl = t >> 5, c = t & 31;
    int n = rb * 8 + nl;
    float v = 0.0f;
    #pragma unroll
    for (int j = 0; j < 16; j++) v += x[n*16 + j] * ew[j*32 + c];
    v *= 0.25f;
    hs[nl*32 + c] = v;
    h[(size_t)n*80 + c] = v;
    for (int idx = t; idx < 8*48; idx += 256) {
      int nn = rb * 8 + idx / 48;
      h[(size_t)nn*80 + 32 + idx % 48] = 0.0f;
    }
    __syncthreads();
    for (int idx = t; idx < 2*8*80; idx += 256) {
      int which = idx / 640, r = idx % 640;
      int nl2 = r / 80, cc = r % 80;
      int n2 = rb * 8 + nl2;
      float o = 0.0f;
      if (cc < 32) {
        const float* W = which ? sws0 : lws0;
        #pragma unroll 8
        for (int u = 0; u < 32; u++) o += hs[nl2*32 + u] * W[u*32 + cc];
        o *= 0.17677669529663687f;
      }
      if (which) xself[(size_t)n2*80 + cc] = o;
      else       hx[(size_t)n2*80 + cc] = (_Float16)o;
    }
  }
}

// ---------------- fused MFMA weight-GEMM (f16) + tensor product -> msg (CSR order) ----
// R16-EXACT K-loop — FROZEN, incl. 4-deep prefetch AND f32 LDS operand formats.
// Structural finding (R23/R25/R26/R28): kernel runs at 116 VGPR against a hard
// 128-VGPR allocator budget under (256,2) — ~12 VGPR headroom. Every lever that
// adds live state trips the cliff: 3rd VMEM stream (R23, -50%), +4 prefetch slots
// (R25 spill; R26 at (256,1): 256 VGPR + 372MB scratch), f16 LDS conversion temps
// (R28: 128 VGPR + 25.6MB scratch, occupancy unchanged). Compiler-enforced local
// minimum at ~13% MfmaUtil.
// R24 (kept, verified): bias in LDS, vectorized conflict-free hx gather
// (conflicts 3.86M->442K): e = lane, stride-1 LDS writes, two half8 loads/thread.
__launch_bounds__(256, 2)
__global__ void edge_msg_kernel(const int* __restrict__ ei, const float* __restrict__ egeo,
                                const _Float16* __restrict__ f_h,
                                const _Float16* __restrict__ hx,
                                const _Float16* __restrict__ w3h,
                                const float* __restrict__ b3g,
                                const int* __restrict__ epos,
                                _Float16* __restrict__ msg, int l) {
  __shared__ float smem[15616];            // 62.5 KB
  __shared__ int eposS[64];
  float* sT    = smem;                     // [32][64]
  float* p2T   = smem + 2048;              // [16][64]
  float* q3T   = smem + 3072;              // [48][64]  s_u * y1_i
  float* vT    = smem + 6144;              // [48][64]
  float* q5T   = smem + 9216;              // [48][64]
  float* biasL = smem + 12288;             // [3328]
  float* poolA = smem;                     // post-loop overlay (sT+p2T dead)
  float* poolB = smem + 3072;              // overlay (q3T dead)
  float* poolC = smem + 6144;              // overlay (vT dead)

  const int t = threadIdx.x;
  const int e0 = blockIdx.x * 64;
  const float* b3l = b3g + (size_t)l * WNUM;

  // ---- prologue ----
  for (int i = t; i < WNUM; i += 256) biasL[i] = b3l[i];
  if (t < 64) eposS[t] = epos[e0 + t];
  // vectorized hx gather: e = lane (stride-1 LDS writes, conflict-free; cb wave-uniform)
  for (int idx = t; idx < 64*5; idx += 256) {
    int e = idx & 63, cb = idx >> 6;       // cb in 0..4, 16 channels each
    int src = ei[e0 + e];
    const half8* hp = (const half8*)(hx + (size_t)src*80 + cb*16);
    half8 v0 = hp[0], v1 = hp[1];
    #pragma unroll
    for (int k = 0; k < 8; ++k) {
      int c = cb*16 + k;
      float f = (float)v0[k];
      if (c < 32) sT[c*64 + e] = f; else vT[(c-32)*64 + e] = f;
    }
    #pragma unroll
    for (int k = 0; k < 8; ++k) {
      int c = cb*16 + 8 + k;
      float f = (float)v1[k];
      if (c < 32) sT[c*64 + e] = f; else vT[(c-32)*64 + e] = f;
    }
  }
  __syncthreads();
  for (int idx = t; idx < 64*16; idx += 256) {
    int u = idx >> 6, e = idx & 63;
    const float* g = &egeo[(size_t)(e0+e)*20];
    float a = vT[(u*3)*64+e]*g[0] + vT[(u*3+1)*64+e]*g[1] + vT[(u*3+2)*64+e]*g[2];
    p2T[u*64 + e] = a * 0.5773502691896258f;
  }
  for (int idx = t; idx < 64*48; idx += 256) {
    int o = idx >> 6, e = idx & 63;
    int u = o / 3, jj = o % 3;
    const float* g = &egeo[(size_t)(e0+e)*20];
    q3T[o*64 + e] = sT[u*64 + e] * g[jj];
    float a = vT[(u*3)*64+e]*g[3+jj] + vT[(u*3+1)*64+e]*g[6+jj] + vT[(u*3+2)*64+e]*g[9+jj];
    q5T[o*64 + e] = a * 0.7745966692414834f;
  }

  const int wv = t >> 6, lane = t & 63, L = lane & 15, quad = lane >> 4;
  const int qb = quad * 4;

  // A fragments for all 4 edge-groups (32 VGPR)
  half8 Ah[4][2];
  #pragma unroll
  for (int g = 0; g < 4; ++g) {
    const half8* fA = (const half8*)(f_h + (size_t)(e0 + g*16 + L)*64);
    Ah[g][0] = fA[quad];
    Ah[g][1] = fA[4 + quad];
  }
  __syncthreads();   // LDS (factors + bias + epos) ready

  const _Float16* wb = w3h + (size_t)l * 208 * 1024 + lane * 8;
  half8 pb0[4], pb1[4];
  float bs[4];

#define PRIME(START)                                                          \
  { _Pragma("unroll")                                                         \
    for (int _s = 0; _s < 4; ++_s) {                                          \
      const _Float16* _wn = wb + (size_t)((START) + _s) * 1024;               \
      pb0[_s] = *(const half8*)_wn;                                           \
      pb1[_s] = *(const half8*)(_wn + 512);                                   \
      bs[_s] = biasL[((START) + _s)*16 + L];                                  \
    } }

  // declares a0..a3 (one per edge-group); CO compile-time
#define GCORE(IDX, CO, OKCOND)                                                \
  f32x4 a0, a1, a2, a3;                                                       \
  { half8 _B0 = pb0[(CO)&3], _B1 = pb1[(CO)&3];                               \
    float _bb = bs[(CO)&3];                                                   \
    if (OKCOND) {                                                             \
      const _Float16* _wn = wb + (size_t)((IDX) + 4) * 1024;                  \
      pb0[(CO)&3] = *(const half8*)_wn;                                       \
      pb1[(CO)&3] = *(const half8*)(_wn + 512);                               \
      bs[(CO)&3] = biasL[((IDX) + 4)*16 + L];                                 \
    }                                                                         \
    a0 = (f32x4){_bb,_bb,_bb,_bb}; a1 = a0; a2 = a0; a3 = a0;                 \
    a0 = __builtin_amdgcn_mfma_f32_16x16x32_f16(Ah[0][0], _B0, a0, 0,0,0);    \
    a0 = __builtin_amdgcn_mfma_f32_16x16x32_f16(Ah[0][1], _B1, a0, 0,0,0);    \
    a1 = __builtin_amdgcn_mfma_f32_16x16x32_f16(Ah[1][0], _B0, a1, 0,0,0);    \
    a1 = __builtin_amdgcn_mfma_f32_16x16x32_f16(Ah[1][1], _B1, a1, 0,0,0);    \
    a2 = __builtin_amdgcn_mfma_f32_16x16x32_f16(Ah[2][0], _B0, a2, 0,0,0);    \
    a2 = __builtin_amdgcn_mfma_f32_16x16x32_f16(Ah[2][1], _B1, a2, 0,0,0);    \
    a3 = __builtin_amdgcn_mfma_f32_16x16x32_f16(Ah[3][0], _B0, a3, 0,0,0);    \
    a3 = __builtin_amdgcn_mfma_f32_16x16x32_f16(Ah[3][1], _B1, a3, 0,0,0);    \
  }

  const float S48 = 0.14433756729740645f;  // 1/sqrt(48)
  const float S64 = 0.125f;                // 1/sqrt(64)

  if (wv <= 1) {
    f32x4 ms[4][3];
    #pragma unroll
    for (int g = 0; g < 4; ++g)
      #pragma unroll
      for (int j = 0; j < 3; ++j) ms[g][j] = (f32x4){0,0,0,0};
    const int ustart = wv * 16, istart = wv * 48, iend = istart + 48;
    PRIME(istart);
    for (int u4 = 0; u4 < 16; u4 += 4) {
      #pragma unroll
      for (int uu = 0; uu < 4; ++uu) {
        const int u = u4 + uu;
        f32x4 f0 = *(const f32x4*)&sT[(ustart+u)*64 + qb];
        f32x4 f1 = *(const f32x4*)&sT[(ustart+u)*64 + 16 + qb];
        f32x4 f2 = *(const f32x4*)&sT[(ustart+u)*64 + 32 + qb];
        f32x4 f3 = *(const f32x4*)&sT[(ustart+u)*64 + 48 + qb];
        #pragma unroll
        for (int j = 0; j < 3; ++j) {
          const int CO = uu*3 + j;
          const int idx = istart + u4*3 + CO;
          GCORE(idx, CO, idx + 4 < iend);
          ms[0][j] += f0*a0; ms[1][j] += f1*a1; ms[2][j] += f2*a2; ms[3][j] += f3*a3;
        }
      }
    }
    float* pool = (wv == 0) ? poolA : poolB;
    __syncthreads();
    #pragma unroll
    for (int g = 0; g < 4; ++g)
      #pragma unroll
      for (int j = 0; j < 3; ++j)
        #pragma unroll
        for (int r = 0; r < 4; ++r)
          pool[(g*16 + qb + r)*48 + j*16 + L] = ms[g][j][r];
    __syncthreads();
  } else if (wv == 2) {
    f32x4 ms[4][3], mv[4][3];
    #pragma unroll
    for (int g = 0; g < 4; ++g)
      #pragma unroll
      for (int j = 0; j < 3; ++j) { ms[g][j] = (f32x4){0,0,0,0}; mv[g][j] = (f32x4){0,0,0,0}; }
    PRIME(96);
    for (int u4 = 0; u4 < 16; u4 += 4) {
      #pragma unroll
      for (int uu = 0; uu < 4; ++uu) {
        const int u = u4 + uu;
        f32x4 f0 = *(const f32x4*)&p2T[u*64 + qb];
        f32x4 f1 = *(const f32x4*)&p2T[u*64 + 16 + qb];
        f32x4 f2 = *(const f32x4*)&p2T[u*64 + 32 + qb];
        f32x4 f3 = *(const f32x4*)&p2T[u*64 + 48 + qb];
        #pragma unroll
        for (int j = 0; j < 3; ++j) {
          const int CO = uu*3 + j;
          const int idx = 96 + u4*3 + CO;
          GCORE(idx, CO, idx + 4 < 144);
          ms[0][j] += f0*a0; ms[1][j] += f1*a1; ms[2][j] += f2*a2; ms[3][j] += f3*a3;
        }
      }
    }
    PRIME(176);
    for (int u4 = 0; u4 < 16; u4 += 4) {
      #pragma unroll
      for (int uu = 0; uu < 4; ++uu) {
        const int u = u4 + uu;
        const int idx = 176 + u;
        GCORE(idx, uu, idx + 4 < 192);
        #pragma unroll
        for (int i = 0; i < 3; ++i) {
          mv[0][i] += *(const f32x4*)&vT[(u*3+i)*64 + qb]      * a0;
          mv[1][i] += *(const f32x4*)&vT[(u*3+i)*64 + 16 + qb] * a1;
          mv[2][i] += *(const f32x4*)&vT[(u*3+i)*64 + 32 + qb] * a2;
          mv[3][i] += *(const f32x4*)&vT[(u*3+i)*64 + 48 + qb] * a3;
        }
      }
    }
    __syncthreads();
    #pragma unroll
    for (int g = 0; g < 4; ++g)
      #pragma unroll
      for (int i = 0; i < 3; ++i)
        #pragma unroll
        for (int r = 0; r < 4; ++r)
          poolC[(g*16 + qb + r)*48 + i*16 + L] = mv[g][i][r];
    __syncthreads();
    #pragma unroll
    for (int g = 0; g < 4; ++g) {
      #pragma unroll
      for (int r = 0; r < 4; ++r) {
        const int eb = g*16 + qb + r;
        _Float16* mp = msg + (size_t)eposS[eb]*96;
        #pragma unroll
        for (int j = 0; j < 3; ++j)
          mp[j*16 + L] = (_Float16)((ms[g][j][r] + poolA[eb*48 + j*16 + L] + poolB[eb*48 + j*16 + L]) * S48);
      }
    }
  } else {
    f32x4 mv[4][3];
    #pragma unroll
    for (int g = 0; g < 4; ++g)
      #pragma unroll
      for (int i = 0; i < 3; ++i) mv[g][i] = (f32x4){0,0,0,0};
    PRIME(144);
    for (int u4 = 0; u4 < 32; u4 += 4) {
      #pragma unroll
      for (int uu = 0; uu < 4; ++uu) {
        const int u = u4 + uu;
        const int idx = 144 + u;
        GCORE(idx, uu, idx + 4 < 176);
        #pragma unroll
        for (int i = 0; i < 3; ++i) {
          mv[0][i] += *(const f32x4*)&q3T[(u*3+i)*64 + qb]      * a0;
          mv[1][i] += *(const f32x4*)&q3T[(u*3+i)*64 + 16 + qb] * a1;
          mv[2][i] += *(const f32x4*)&q3T[(u*3+i)*64 + 32 + qb] * a2;
          mv[3][i] += *(const f32x4*)&q3T[(u*3+i)*64 + 48 + qb] * a3;
        }
      }
    }
    PRIME(192);
    for (int u4 = 0; u4 < 16; u4 += 4) {
      #pragma unroll
      for (int uu = 0; uu < 4; ++uu) {
        const int u = u4 + uu;
        const int idx = 192 + u;
        GCORE(idx, uu, idx + 4 < 208);
        #pragma unroll
        for (int i = 0; i < 3; ++i) {
          mv[0][i] += *(const f32x4*)&q5T[(u*3+i)*64 + qb]      * a0;
          mv[1][i] += *(const f32x4*)&q5T[(u*3+i)*64 + 16 + qb] * a1;
          mv[2][i] += *(const f32x4*)&q5T[(u*3+i)*64 + 32 + qb] * a2;
          mv[3][i] += *(const f32x4*)&q5T[(u*3+i)*64 + 48 + qb] * a3;
        }
      }
    }
    __syncthreads();
    __syncthreads();
    #pragma unroll
    for (int g = 0; g < 4; ++g) {
      #pragma unroll
      for (int r = 0; r < 4; ++r) {
        const int eb = g*16 + qb + r;
        _Float16* mp = msg + (size_t)eposS[eb]*96;
        #pragma unroll
        for (int i = 0; i < 3; ++i)
          mp[48 + 3*L + i] = (_Float16)((mv[g][i][r] + poolC[eb*48 + i*16 + L]) * S64);
      }
    }
  }
#undef GCORE
#undef PRIME
}

// ---------------- fused: CSR-streaming gather (f16 msg) + node update + next linears ----
// R29 (confirmed by R13-vs-R14 same-machine A/B: 419.4 vs 436.2 us): gather loop
// 2-way -> 4-way independent accumulators (MLP for the serial dependent-load chain).
__global__ void agg_fused_kernel(const _Float16* __restrict__ msg, const int* __restrict__ offs,
                                 const float* __restrict__ xself_in, float* __restrict__ h,
                                 const float* __restrict__ lwsN, const float* __restrict__ lwvN,
                                 const float* __restrict__ swsN, const float* __restrict__ swvN,
                                 _Float16* __restrict__ hx_out, float* __restrict__ xself_out,
                                 const float* __restrict__ pw, float* __restrict__ out,
                                 int last) {
  __shared__ float sagg[4][96];
  __shared__ float hnew[4][80];
  int t = threadIdx.x;
  int nb = blockIdx.x * 4;
  for (int idx = t; idx < 4*96; idx += 256) {
    int nl = idx / 96, c = idx % 96;
    int n = nb + nl;
    int b = offs[n], e = offs[n+1];
    float a0 = 0.0f, a1 = 0.0f, a2 = 0.0f, a3 = 0.0f;
    int j = b;
    for (; j + 3 < e; j += 4) {
      a0 += (float)msg[(size_t)j*96 + c];
      a1 += (float)msg[(size_t)(j+1)*96 + c];
      a2 += (float)msg[(size_t)(j+2)*96 + c];
      a3 += (float)msg[(size_t)(j+3)*96 + c];
    }
    for (; j < e; ++j) a0 += (float)msg[(size_t)j*96 + c];
    sagg[nl][c] = ((a0 + a1) + (a2 + a3)) * 0.20412414523193154f;   // 1/sqrt(24)
  }
  __syncthreads();
  for (int idx = t; idx < 4*80; idx += 256) {
    int nl = idx / 80, c = idx % 80;
    int n = nb + nl;
    float a;
    if (c < 32) {
      a = silu_f(sagg[nl][c]);
    } else {
      int oc = c - 32, wch = oc / 3;
      a = sagg[nl][48 + oc] * sigm_f(sagg[nl][32 + wch]);
    }
    float hn = h[(size_t)n*80 + c] + xself_in[(size_t)n*80 + c] + a;
    hnew[nl][c] = hn;
    h[(size_t)n*80 + c] = hn;
  }
  __syncthreads();
  if (!last) {
    for (int idx = t; idx < 2*4*80; idx += 256) {
      int which = idx / 320, r = idx % 320;
      int nl = r / 80, c = r % 80;
      int n = nb + nl;
      const float* Ws = which ? swsN : lwsN;
      const float* Wv = which ? swvN : lwvN;
      float v = 0.0f;
      if (c < 32) {
        #pragma unroll 8
        for (int u = 0; u < 32; u++) v += hnew[nl][u] * Ws[u*32 + c];
        v *= 0.17677669529663687f;
      } else {
        int oc = c - 32, wch = oc / 3, i = oc % 3;
        #pragma unroll
        for (int u = 0; u < 16; u++) v += hnew[nl][32 + u*3 + i] * Wv[u*16 + wch];
        v *= 0.25f;
      }
      if (which) xself_out[(size_t)n*80 + c] = v;
      else       hx_out[(size_t)n*80 + c] = (_Float16)v;
    }
  } else {
    for (int idx = t; idx < 4*32; idx += 256) {
      int nl = idx / 32, c = idx % 32;
      int n = nb + nl;
      float acc = 0.0f;
      #pragma unroll 8
      for (int u = 0; u < 32; u++) acc += hnew[nl][u] * pw[u*32 + c];
      out[(size_t)n*32 + c] = acc * 0.17677669529663687f;
    }
  }
}

extern "C" void kernel_launch(void* const* d_in, const int* in_sizes, int n_in,
                              void* d_out, int out_size, void* d_ws, size_t ws_size,
                              hipStream_t stream) {
  const float* x       = (const float*)d_in[0];
  const float* pos     = (const float*)d_in[1];
  const int*   ei      = (const int*)  d_in[2];
  const float* embed_w = (const float*)d_in[3];
  const float* proj_w  = (const float*)d_in[4];
  const float* lin_ws  = (const float*)d_in[5];
  const float* lin_wv  = (const float*)d_in[6];
  const float* sc_ws   = (const float*)d_in[7];
  const float* sc_wv   = (const float*)d_in[8];
  const float* mlp_w1  = (const float*)d_in[9];
  const float* mlp_b1  = (const float*)d_in[10];
  const float* mlp_w2  = (const float*)d_in[11];
  const float* mlp_b2  = (const float*)d_in[12];
  const float* mlp_w3  = (const float*)d_in[13];
  const float* mlp_b3  = (const float*)d_in[14];
  float* out = (float*)d_out;

  float* ws    = (float*)d_ws;
  float* egeo  = ws;                          // NE*20
  float* h     = egeo  + (size_t)NE*20;       // NN*80
  float* xself = h     + (size_t)NN*80;       // NN*80
  _Float16* hx  = (_Float16*)(xself + (size_t)NN*80); // NN*80 f16
  _Float16* msg = hx + (size_t)NN*80;                 // NE*96 f16 (CSR-ordered rows)
  _Float16* f_h = msg + (size_t)NE*96;                // 4*NE*64 f16 (all layers)
  _Float16* w3h = f_h + (size_t)4*NE*64;              // 4*208*1024 f16
  _Float16* w2h = w3h + (size_t)4*208*1024;           // 16384 f16 (32 KB)
  int* cnt    = (int*)(w2h + 16384);          // NN
  int* offs   = cnt + NN;                     // NN+1
  int* cursor = offs + NN + 1;                // NN
  int* epos   = cursor + NN;                  // NE

  hipMemsetAsync(cnt, 0, NN*sizeof(int), stream);
  geom_w2_kernel<<<GB_GEO + 64, 256, 0, stream>>>(pos, ei, egeo, cnt, mlp_w2, w2h);
  scan_kernel<<<1, 256, 0, stream>>>(cnt, offs, cursor);
  prologue_fused_kernel<<<PB_SCAT + PB_W3 + PB_RAD + PB_EMB, 256, 0, stream>>>(
      ei, cursor, epos, mlp_w3, w3h, w2h, egeo,
      mlp_w1, mlp_b1, mlp_b2, f_h, x, embed_w, lin_ws, sc_ws, h, hx, xself);

  for (int l = 0; l < 4; l++) {
    edge_msg_kernel<<<NE/64, 256, 0, stream>>>(ei, egeo, f_h + (size_t)l*NE*64, hx,
                                               w3h, mlp_b3, epos, msg, l);
    int last = (l == 3);
    agg_fused_kernel<<<NN/4, 256, 0, stream>>>(
        msg, offs, xself, h,
        lin_ws + (size_t)(l+1 < 4 ? l+1 : 0) * 1024,
        lin_wv + (size_t)(l+1 < 4 ? l+1 : 0) * 256,
        sc_ws  + (size_t)(l+1 < 4 ? l+1 : 0) * 1024,
        sc_wv  + (size_t)(l+1 < 4 ? l+1 : 0) * 256,
        hx, xself, proj_w, out, last);
  }
}